// Round 2
// baseline (592.979 us; speedup 1.0000x reference)
//
#include <hip/hip_runtime.h>
#include <hip/hip_fp16.h>

#define NP 100000
#define KA 3.2188758248682006f   // -2*ln(0.2)
#define KB 0.44628710262841953f  // -2*ln(0.8)

// workspace layout in __half2 units: planes transposed to [H][W][16] (feature pairs)
#define SS_CNT 262144   // 128*128*16
#define ST_CNT 204800   // 128*100*16
#define OFF0 0
#define OFF1 (OFF0 + SS_CNT)
#define OFF2 (OFF1 + SS_CNT)
#define OFF3 (OFF2 + ST_CNT)
#define OFF4 (OFF3 + SS_CNT)
#define OFF5 (OFF4 + ST_CNT)

__device__ __forceinline__ int clampi(int v, int hi){ v = v < 0 ? 0 : v; return v > hi ? hi : v; }

struct Dim { int i0, i1; float fr; };

__device__ __forceinline__ Dim mkdim(float g, int hi){
  float fl = floorf(g);
  Dim d;
  d.fr = g - fl;            // unclipped fractional weight (faithful to reference)
  int i = (int)fl;
  d.i0 = clampi(i, hi);
  d.i1 = clampi(i + 1, hi);
  return d;
}

__device__ __forceinline__ void bilin(const __half2* __restrict__ P, int W,
                                      Dim X, Dim Y, int fp, float2& acc){
  int r0 = Y.i0 * W, r1 = Y.i1 * W;
  __half2 h00 = P[(r0 + X.i0) * 16 + fp];
  __half2 h01 = P[(r0 + X.i1) * 16 + fp];
  __half2 h10 = P[(r1 + X.i0) * 16 + fp];
  __half2 h11 = P[(r1 + X.i1) * 16 + fp];
  float fx = X.fr, fy = Y.fr;
  float gx = 1.0f - fx, gy = 1.0f - fy;
  float w00 = gy * gx, w01 = gy * fx, w10 = fy * gx, w11 = fy * fx;
  float2 a = __half22float2(h00), b = __half22float2(h01);
  float2 c = __half22float2(h10), d = __half22float2(h11);
  acc.x += w00 * a.x + w01 * b.x + w10 * c.x + w11 * d.x;
  acc.y += w00 * a.y + w01 * b.y + w10 * c.y + w11 * d.y;
}

__device__ __forceinline__ void process_sample(const __half2* __restrict__ ws,
    float sx, float sy, float sz, float tval, int fp, float2* acc){
  // world -> grid: s_norm = -0.625*s ; g = (s_norm+1)*0.5*(128-1) = 63.5 - 39.6875*s
  Dim d0 = mkdim(fmaf(sx, -39.6875f, 63.5f), 127);
  Dim d1 = mkdim(fmaf(sy, -39.6875f, 63.5f), 127);
  Dim d2 = mkdim(fmaf(sz, -39.6875f, 63.5f), 127);
  // t grid: tc = 2t-1 ; g = (tc+1)*0.5*(100-1) = 99*t
  Dim dt = mkdim(tval * 99.0f, 99);
  bilin(ws + OFF0, 128, d0, d1, fp, acc[0]);   // plane0: x=s0, y=s1
  bilin(ws + OFF1, 128, d0, d2, fp, acc[1]);   // plane1: x=s0, y=s2
  bilin(ws + OFF2, 100, dt, d0, fp, acc[2]);   // plane2: x=t,  y=s0
  bilin(ws + OFF3, 128, d1, d2, fp, acc[3]);   // plane3: x=s1, y=s2
  bilin(ws + OFF4, 100, dt, d1, fp, acc[4]);   // plane4: x=t,  y=s1
  bilin(ws + OFF5, 100, dt, d2, fp, acc[5]);   // plane5: x=t,  y=s2
}

__device__ __forceinline__ float3 eigvec3(float c00,float c01,float c02,
                                          float c11,float c12,float c22,float lam){
  float m00 = c00 - lam, m11 = c11 - lam, m22 = c22 - lam;
  // cross products of rows of (C - lam I); pick largest for stability
  float ux0 = c01*c12 - c02*m11, uy0 = c02*c01 - m00*c12, uz0 = m00*m11 - c01*c01;
  float ux1 = c01*m22 - c02*c12, uy1 = c02*c02 - m00*m22, uz1 = m00*c12 - c01*c02;
  float ux2 = m11*m22 - c12*c12, uy2 = c12*c02 - c01*m22, uz2 = c01*c12 - m11*c02;
  float n0 = ux0*ux0 + uy0*uy0 + uz0*uz0;
  float n1 = ux1*ux1 + uy1*uy1 + uz1*uz1;
  float n2 = ux2*ux2 + uy2*uy2 + uz2*uz2;
  float ux = ux0, uy = uy0, uz = uz0, nn = n0;
  if (n1 > nn){ ux = ux1; uy = uy1; uz = uz1; nn = n1; }
  if (n2 > nn){ ux = ux2; uy = uy2; uz = uz2; nn = n2; }
  float inv = 1.0f / sqrtf(nn + 1e-45f);
  return make_float3(ux*inv, uy*inv, uz*inv);
}

__global__ void wpf_transpose(const float* __restrict__ p0, const float* __restrict__ p1,
                              const float* __restrict__ p2, const float* __restrict__ p3,
                              const float* __restrict__ p4, const float* __restrict__ p5,
                              __half2* __restrict__ ws, float* __restrict__ coltime)
{
  int plane = blockIdx.y;
  if (plane == 0 && blockIdx.x == 0 && threadIdx.x == 0) coltime[0] = 1.0f;
  int idx = blockIdx.x * blockDim.x + threadIdx.x;
  const float* src; int cnt, off, HW;
  switch (plane){
    case 0:  src = p0; cnt = SS_CNT; off = OFF0; HW = 16384; break;
    case 1:  src = p1; cnt = SS_CNT; off = OFF1; HW = 16384; break;
    case 2:  src = p2; cnt = ST_CNT; off = OFF2; HW = 12800; break;
    case 3:  src = p3; cnt = SS_CNT; off = OFF3; HW = 16384; break;
    case 4:  src = p4; cnt = ST_CNT; off = OFF4; HW = 12800; break;
    default: src = p5; cnt = ST_CNT; off = OFF5; HW = 12800; break;
  }
  if (idx >= cnt) return;
  int fp = idx & 15, hw = idx >> 4;
  float a = src[(2*fp)     * HW + hw];
  float b = src[(2*fp + 1) * HW + hw];
  ws[off + idx] = __floats2half2_rn(a, b);
}

__global__ __launch_bounds__(256) void wpf_main(
    const float* __restrict__ pts, const float* __restrict__ tim,
    const float* __restrict__ cov6, const __half2* __restrict__ ws,
    float* __restrict__ out)
{
  int tid = blockIdx.x * 256 + threadIdx.x;
  int pt = tid >> 4, fp = tid & 15;
  if (pt >= NP) return;

  float px = pts[pt*3+0], py = pts[pt*3+1], pz = pts[pt*3+2];
  float c00 = cov6[pt*6+0], c01 = cov6[pt*6+1], c02 = cov6[pt*6+2];
  float c11 = cov6[pt*6+3], c12 = cov6[pt*6+4], c22 = cov6[pt*6+5];

  // ---- analytic symmetric 3x3 eigendecomposition, ascending eigenvalues ----
  float q3 = (c00 + c11 + c22) * (1.0f/3.0f);
  float p1 = c01*c01 + c02*c02 + c12*c12;
  float d00 = c00 - q3, d11 = c11 - q3, d22 = c22 - q3;
  float p2 = d00*d00 + d11*d11 + d22*d22 + 2.0f*p1;
  float pp = sqrtf(p2 * (1.0f/6.0f)) + 1e-30f;
  float pinv = 1.0f / pp;
  float b00 = d00*pinv, b11 = d11*pinv, b22 = d22*pinv;
  float b01 = c01*pinv, b02 = c02*pinv, b12 = c12*pinv;
  float detB = b00*(b11*b22 - b12*b12) - b01*(b01*b22 - b12*b02) + b02*(b01*b12 - b11*b02);
  float r = 0.5f * detB;
  r = fminf(1.0f, fmaxf(-1.0f, r));
  float phi = acosf(r) * (1.0f/3.0f);
  float l2 = q3 + 2.0f*pp*cosf(phi);                          // largest
  float l0 = q3 + 2.0f*pp*cosf(phi + 2.0943951023931953f);    // smallest
  float3 v0 = eigvec3(c00,c01,c02,c11,c12,c22, l0);
  float3 v2 = eigvec3(c00,c01,c02,c11,c12,c22, l2);
  float v1x = v2.y*v0.z - v2.z*v0.y;
  float v1y = v2.z*v0.x - v2.x*v0.z;
  float v1z = v2.x*v0.y - v2.y*v0.x;
  float v1inv = 1.0f / sqrtf(v1x*v1x + v1y*v1y + v1z*v1z + 1e-45f);
  v1x *= v1inv; v1y *= v1inv; v1z *= v1inv;

  // normals = rows of V (V columns = v0,v1,v2): normal k = (v0[k], v1[k], v2[k])
  float nx[3] = { v0.x, v0.y, v0.z };
  float ny[3] = { v1x,  v1y,  v1z  };
  float nz[3] = { v2.x, v2.y, v2.z };

  // Cinv via adjugate/det
  float A00 = c11*c22 - c12*c12;
  float A01 = c02*c12 - c01*c22;
  float A02 = c01*c12 - c02*c11;
  float A11 = c00*c22 - c02*c02;
  float A12 = c01*c02 - c00*c12;
  float A22 = c00*c11 - c01*c01;
  float det  = c00*A00 + c01*A01 + c02*A02;
  float dinv = 1.0f / det;
  float i00 = A00*dinv, i01 = A01*dinv, i02 = A02*dinv;
  float i11 = A11*dinv, i12 = A12*dinv, i22 = A22*dinv;

  float ca[3], cb[3];
  #pragma unroll
  for (int k = 0; k < 3; ++k){
    float a = nx[k], b = ny[k], c = nz[k];
    float lam = i00*a*a + i11*b*b + i22*c*c + 2.0f*(i01*a*b + i02*a*c + i12*b*c);
    float linv = 1.0f / lam;
    ca[k] = sqrtf(KA * linv);
    cb[k] = sqrtf(KB * linv);
  }

  // faithful to jnp.tile(t,(13,1)): sample m of point n uses time[(13n+m) % N]
  int tbase = (pt * 13) % NP;

  float2 acc[6];
  #pragma unroll
  for (int i = 0; i < 6; ++i) acc[i] = make_float2(0.0f, 0.0f);

  {
    int ti = tbase; // m = 0
    process_sample(ws, px, py, pz, tim[ti >= NP ? ti - NP : ti], fp, acc);
  }
  #pragma unroll
  for (int k = 0; k < 3; ++k){
    int ti = tbase + 1 + k; if (ti >= NP) ti -= NP;
    process_sample(ws, px + ca[k]*nx[k], py + ca[k]*ny[k], pz + ca[k]*nz[k], tim[ti], fp, acc);
  }
  #pragma unroll
  for (int k = 0; k < 3; ++k){
    int ti = tbase + 4 + k; if (ti >= NP) ti -= NP;
    process_sample(ws, px + cb[k]*nx[k], py + cb[k]*ny[k], pz + cb[k]*nz[k], tim[ti], fp, acc);
  }
  #pragma unroll
  for (int k = 0; k < 3; ++k){
    int ti = tbase + 7 + k; if (ti >= NP) ti -= NP;
    process_sample(ws, px - ca[k]*nx[k], py - ca[k]*ny[k], pz - ca[k]*nz[k], tim[ti], fp, acc);
  }
  #pragma unroll
  for (int k = 0; k < 3; ++k){
    int ti = tbase + 10 + k; if (ti >= NP) ti -= NP;
    process_sample(ws, px - cb[k]*nx[k], py - cb[k]*ny[k], pz - cb[k]*nz[k], tim[ti], fp, acc);
  }

  const float s13 = 1.0f / 13.0f;
  float f0x = acc[0].x*s13, f0y = acc[0].y*s13;
  float f1x = acc[1].x*s13, f1y = acc[1].y*s13;
  float f2x = acc[2].x*s13, f2y = acc[2].y*s13;
  float f3x = acc[3].x*s13, f3y = acc[3].y*s13;
  float f4x = acc[4].x*s13, f4y = acc[4].y*s13;
  float f5x = acc[5].x*s13, f5y = acc[5].y*s13;

  float2 sp = make_float2(f0x*f1x*f3x, f0y*f1y*f3y);
  float2 st = make_float2(f2x*f4x*f5x, f2y*f4y*f5y);

  reinterpret_cast<float2*>(out)[tid] = sp;
  reinterpret_cast<float2*>(out + NP*32)[tid] = st;
}

extern "C" void kernel_launch(void* const* d_in, const int* in_sizes, int n_in,
                              void* d_out, int out_size, void* d_ws, size_t ws_size,
                              hipStream_t stream) {
  (void)in_sizes; (void)n_in; (void)out_size; (void)ws_size;
  const float* pts  = (const float*)d_in[0];
  const float* tim  = (const float*)d_in[1];
  const float* cov6 = (const float*)d_in[2];
  const float* p0 = (const float*)d_in[3];
  const float* p1 = (const float*)d_in[4];
  const float* p2 = (const float*)d_in[5];
  const float* p3 = (const float*)d_in[6];
  const float* p4 = (const float*)d_in[7];
  const float* p5 = (const float*)d_in[8];
  float* out = (float*)d_out;
  __half2* ws = (__half2*)d_ws;

  dim3 tgrid(1024, 6);
  wpf_transpose<<<tgrid, 256, 0, stream>>>(p0, p1, p2, p3, p4, p5, ws, out + 2*NP*32);

  int nthreads = NP * 16;
  wpf_main<<<(nthreads + 255) / 256, 256, 0, stream>>>(pts, tim, cov6, ws, out);
}

// Round 3
// 220.215 us; speedup vs baseline: 2.6927x; 2.6927x over previous
//
#include <hip/hip_runtime.h>
#include <hip/hip_fp16.h>

#define NP 100000
#define PPB 16
#define KA 3.2188758248682006f   // -2*ln(0.2)
#define KB 0.44628710262841953f  // -2*ln(0.8)

// workspace layout in __half2 units: planes transposed to [H][W][16] (feature pairs)
#define SS_CNT 262144   // 128*128*16
#define ST_CNT 204800   // 128*100*16
#define OFF0 0
#define OFF1 (OFF0 + SS_CNT)
#define OFF2 (OFF1 + SS_CNT)
#define OFF3 (OFF2 + ST_CNT)
#define OFF4 (OFF3 + SS_CNT)
#define OFF5 (OFF4 + ST_CNT)

__device__ __forceinline__ int clampi(int v, int hi){ v = v < 0 ? 0 : v; return v > hi ? hi : v; }

struct Dim { int i0, i1; float fr; };

__device__ __forceinline__ Dim mkdim(float g, int hi){
  float fl = floorf(g);
  Dim d;
  d.fr = g - fl;            // unclipped fractional weight (faithful to reference)
  int i = (int)fl;
  d.i0 = clampi(i, hi);
  d.i1 = clampi(i + 1, hi);
  return d;
}

__device__ __forceinline__ void bilin(const __half2* __restrict__ P, int W,
                                      Dim X, Dim Y, int fp, float2& acc){
  int r0 = Y.i0 * W, r1 = Y.i1 * W;
  __half2 h00 = P[(r0 + X.i0) * 16 + fp];
  __half2 h01 = P[(r0 + X.i1) * 16 + fp];
  __half2 h10 = P[(r1 + X.i0) * 16 + fp];
  __half2 h11 = P[(r1 + X.i1) * 16 + fp];
  float fx = X.fr, fy = Y.fr;
  float gx = 1.0f - fx, gy = 1.0f - fy;
  float w00 = gy * gx, w01 = gy * fx, w10 = fy * gx, w11 = fy * fx;
  float2 a = __half22float2(h00), b = __half22float2(h01);
  float2 c = __half22float2(h10), d = __half22float2(h11);
  acc.x += w00 * a.x + w01 * b.x + w10 * c.x + w11 * d.x;
  acc.y += w00 * a.y + w01 * b.y + w10 * c.y + w11 * d.y;
}

__device__ __forceinline__ float3 eigvec3(float c00,float c01,float c02,
                                          float c11,float c12,float c22,float lam){
  float m00 = c00 - lam, m11 = c11 - lam, m22 = c22 - lam;
  float ux0 = c01*c12 - c02*m11, uy0 = c02*c01 - m00*c12, uz0 = m00*m11 - c01*c01;
  float ux1 = c01*m22 - c02*c12, uy1 = c02*c02 - m00*m22, uz1 = m00*c12 - c01*c02;
  float ux2 = m11*m22 - c12*c12, uy2 = c12*c02 - c01*m22, uz2 = c01*c12 - m11*c02;
  float n0 = ux0*ux0 + uy0*uy0 + uz0*uz0;
  float n1 = ux1*ux1 + uy1*uy1 + uz1*uz1;
  float n2 = ux2*ux2 + uy2*uy2 + uz2*uz2;
  float ux = ux0, uy = uy0, uz = uz0, nn = n0;
  if (n1 > nn){ ux = ux1; uy = uy1; uz = uz1; nn = n1; }
  if (n2 > nn){ ux = ux2; uy = uy2; uz = uz2; nn = n2; }
  float inv = 1.0f / sqrtf(nn + 1e-45f);
  return make_float3(ux*inv, uy*inv, uz*inv);
}

// ---- LDS-tile transpose: [32][HW] f32 -> [HW][16] half2, coalesced both ways ----
__global__ __launch_bounds__(256) void wpf_transpose(
    const float* __restrict__ p0, const float* __restrict__ p1,
    const float* __restrict__ p2, const float* __restrict__ p3,
    const float* __restrict__ p4, const float* __restrict__ p5,
    __half2* __restrict__ ws, float* __restrict__ coltime)
{
  __shared__ float tile[32][65];
  int plane = blockIdx.y;
  if (plane == 0 && blockIdx.x == 0 && threadIdx.x == 0) coltime[0] = 1.0f;
  const float* src; int off, HW;
  switch (plane){
    case 0:  src = p0; off = OFF0; HW = 16384; break;
    case 1:  src = p1; off = OFF1; HW = 16384; break;
    case 2:  src = p2; off = OFF2; HW = 12800; break;
    case 3:  src = p3; off = OFF3; HW = 16384; break;
    case 4:  src = p4; off = OFF4; HW = 12800; break;
    default: src = p5; off = OFF5; HW = 12800; break;
  }
  int hw0 = blockIdx.x * 64;
  if (hw0 >= HW) return;
  int hwt = threadIdx.x & 63;
  int fq  = threadIdx.x >> 6;   // 0..3
  #pragma unroll
  for (int i = 0; i < 8; ++i){
    int f = fq * 8 + i;         // 0..31
    tile[f][hwt] = src[f * HW + hw0 + hwt];  // coalesced: 64 consecutive hw per wave
  }
  __syncthreads();
  int fp = threadIdx.x & 15;
  int hb = threadIdx.x >> 4;    // 0..15
  #pragma unroll
  for (int i = 0; i < 4; ++i){
    int hl = i * 16 + hb;       // 0..63
    float a = tile[2*fp][hl], b = tile[2*fp+1][hl];
    ws[off + (hw0 + hl) * 16 + fp] = __floats2half2_rn(a, b);  // coalesced 256B/wave
  }
}

// ---- main: phase1 geometry (16 threads) -> LDS, phase2 gather (256 threads) ----
__global__ __launch_bounds__(256, 4) void wpf_main(
    const float* __restrict__ pts, const float* __restrict__ tim,
    const float* __restrict__ cov6, const __half2* __restrict__ ws,
    float* __restrict__ out)
{
  __shared__ float4 smp[PPB][13];   // grid-space (gx,gy,gz,gt) per sample
  int tidl = threadIdx.x;
  int pbase = blockIdx.x * PPB;

  if (tidl < PPB){
    int pt = pbase + tidl;
    float px = pts[pt*3+0], py = pts[pt*3+1], pz = pts[pt*3+2];
    float c00 = cov6[pt*6+0], c01 = cov6[pt*6+1], c02 = cov6[pt*6+2];
    float c11 = cov6[pt*6+3], c12 = cov6[pt*6+4], c22 = cov6[pt*6+5];

    // analytic symmetric 3x3 eigendecomposition, ascending eigenvalues
    float q3 = (c00 + c11 + c22) * (1.0f/3.0f);
    float p1 = c01*c01 + c02*c02 + c12*c12;
    float d00 = c00 - q3, d11 = c11 - q3, d22 = c22 - q3;
    float p2 = d00*d00 + d11*d11 + d22*d22 + 2.0f*p1;
    float pp = sqrtf(p2 * (1.0f/6.0f)) + 1e-30f;
    float pinv = 1.0f / pp;
    float b00 = d00*pinv, b11 = d11*pinv, b22 = d22*pinv;
    float b01 = c01*pinv, b02 = c02*pinv, b12 = c12*pinv;
    float detB = b00*(b11*b22 - b12*b12) - b01*(b01*b22 - b12*b02) + b02*(b01*b12 - b11*b02);
    float r = fminf(1.0f, fmaxf(-1.0f, 0.5f * detB));
    float phi = acosf(r) * (1.0f/3.0f);
    float l2 = q3 + 2.0f*pp*cosf(phi);                          // largest
    float l0 = q3 + 2.0f*pp*cosf(phi + 2.0943951023931953f);    // smallest
    float3 v0 = eigvec3(c00,c01,c02,c11,c12,c22, l0);
    float3 v2 = eigvec3(c00,c01,c02,c11,c12,c22, l2);
    float v1x = v2.y*v0.z - v2.z*v0.y;
    float v1y = v2.z*v0.x - v2.x*v0.z;
    float v1z = v2.x*v0.y - v2.y*v0.x;
    float v1inv = 1.0f / sqrtf(v1x*v1x + v1y*v1y + v1z*v1z + 1e-45f);
    v1x *= v1inv; v1y *= v1inv; v1z *= v1inv;

    // normals = rows of V (V columns v0,v1,v2): n_k = (v0[k], v1[k], v2[k])
    float nx[3] = { v0.x, v0.y, v0.z };
    float ny[3] = { v1x,  v1y,  v1z  };
    float nz[3] = { v2.x, v2.y, v2.z };

    // Cinv via adjugate/det
    float A00 = c11*c22 - c12*c12;
    float A01 = c02*c12 - c01*c22;
    float A02 = c01*c12 - c02*c11;
    float A11 = c00*c22 - c02*c02;
    float A12 = c01*c02 - c00*c12;
    float A22 = c00*c11 - c01*c01;
    float det  = c00*A00 + c01*A01 + c02*A02;
    float dinv = 1.0f / det;
    float i00 = A00*dinv, i01 = A01*dinv, i02 = A02*dinv;
    float i11 = A11*dinv, i12 = A12*dinv, i22 = A22*dinv;

    // grid-space center and scaled offsets: grid = 63.5 - 39.6875*world
    float gpx = fmaf(px, -39.6875f, 63.5f);
    float gpy = fmaf(py, -39.6875f, 63.5f);
    float gpz = fmaf(pz, -39.6875f, 63.5f);
    float axA[3], ayA[3], azA[3], axB[3], ayB[3], azB[3];
    #pragma unroll
    for (int k = 0; k < 3; ++k){
      float a = nx[k], b = ny[k], c = nz[k];
      float lam = i00*a*a + i11*b*b + i22*c*c + 2.0f*(i01*a*b + i02*a*c + i12*b*c);
      float linv = 1.0f / lam;
      float sA = -39.6875f * sqrtf(KA * linv);
      float sB = -39.6875f * sqrtf(KB * linv);
      axA[k] = sA*a; ayA[k] = sA*b; azA[k] = sA*c;
      axB[k] = sB*a; ayB[k] = sB*b; azB[k] = sB*c;
    }

    // faithful to jnp.tile(t,(13,1)): sample m of point n uses time[(13n+m) % N]
    int tb = (pt * 13) % NP;
    int ti = tb;
    smp[tidl][0] = make_float4(gpx, gpy, gpz, tim[ti] * 99.0f);
    #pragma unroll
    for (int k = 0; k < 3; ++k){
      ti = tb + 1 + k; if (ti >= NP) ti -= NP;
      smp[tidl][1+k]  = make_float4(gpx+axA[k], gpy+ayA[k], gpz+azA[k], tim[ti]*99.0f);
    }
    #pragma unroll
    for (int k = 0; k < 3; ++k){
      ti = tb + 4 + k; if (ti >= NP) ti -= NP;
      smp[tidl][4+k]  = make_float4(gpx+axB[k], gpy+ayB[k], gpz+azB[k], tim[ti]*99.0f);
    }
    #pragma unroll
    for (int k = 0; k < 3; ++k){
      ti = tb + 7 + k; if (ti >= NP) ti -= NP;
      smp[tidl][7+k]  = make_float4(gpx-axA[k], gpy-ayA[k], gpz-azA[k], tim[ti]*99.0f);
    }
    #pragma unroll
    for (int k = 0; k < 3; ++k){
      ti = tb + 10 + k; if (ti >= NP) ti -= NP;
      smp[tidl][10+k] = make_float4(gpx-axB[k], gpy-ayB[k], gpz-azB[k], tim[ti]*99.0f);
    }
  }
  __syncthreads();

  int lp = tidl >> 4, fp = tidl & 15;
  const __half2* __restrict__ w0 = ws + OFF0;
  const __half2* __restrict__ w1 = ws + OFF1;
  const __half2* __restrict__ w2 = ws + OFF2;
  const __half2* __restrict__ w3 = ws + OFF3;
  const __half2* __restrict__ w4 = ws + OFF4;
  const __half2* __restrict__ w5 = ws + OFF5;

  float2 acc[6];
  #pragma unroll
  for (int i = 0; i < 6; ++i) acc[i] = make_float2(0.0f, 0.0f);

  #pragma unroll 2
  for (int m = 0; m < 13; ++m){
    float4 s = smp[lp][m];
    Dim d0 = mkdim(s.x, 127);
    Dim d1 = mkdim(s.y, 127);
    Dim d2 = mkdim(s.z, 127);
    Dim dt = mkdim(s.w, 99);
    bilin(w0, 128, d0, d1, fp, acc[0]);   // plane0: x=s0, y=s1
    bilin(w1, 128, d0, d2, fp, acc[1]);   // plane1: x=s0, y=s2
    bilin(w2, 100, dt, d0, fp, acc[2]);   // plane2: x=t,  y=s0
    bilin(w3, 128, d1, d2, fp, acc[3]);   // plane3: x=s1, y=s2
    bilin(w4, 100, dt, d1, fp, acc[4]);   // plane4: x=t,  y=s1
    bilin(w5, 100, dt, d2, fp, acc[5]);   // plane5: x=t,  y=s2
  }

  const float s13 = 1.0f / 13.0f;
  float f0x = acc[0].x*s13, f0y = acc[0].y*s13;
  float f1x = acc[1].x*s13, f1y = acc[1].y*s13;
  float f2x = acc[2].x*s13, f2y = acc[2].y*s13;
  float f3x = acc[3].x*s13, f3y = acc[3].y*s13;
  float f4x = acc[4].x*s13, f4y = acc[4].y*s13;
  float f5x = acc[5].x*s13, f5y = acc[5].y*s13;

  float2 sp = make_float2(f0x*f1x*f3x, f0y*f1y*f3y);
  float2 st = make_float2(f2x*f4x*f5x, f2y*f4y*f5y);

  int gid = blockIdx.x * 256 + tidl;   // == (pbase+lp)*16 + fp
  reinterpret_cast<float2*>(out)[gid] = sp;
  reinterpret_cast<float2*>(out + NP*32)[gid] = st;
}

extern "C" void kernel_launch(void* const* d_in, const int* in_sizes, int n_in,
                              void* d_out, int out_size, void* d_ws, size_t ws_size,
                              hipStream_t stream) {
  (void)in_sizes; (void)n_in; (void)out_size; (void)ws_size;
  const float* pts  = (const float*)d_in[0];
  const float* tim  = (const float*)d_in[1];
  const float* cov6 = (const float*)d_in[2];
  const float* p0 = (const float*)d_in[3];
  const float* p1 = (const float*)d_in[4];
  const float* p2 = (const float*)d_in[5];
  const float* p3 = (const float*)d_in[6];
  const float* p4 = (const float*)d_in[7];
  const float* p5 = (const float*)d_in[8];
  float* out = (float*)d_out;
  __half2* ws = (__half2*)d_ws;

  dim3 tgrid(256, 6);   // 256 hw-tiles of 64 (SS planes use all, ST use 200)
  wpf_transpose<<<tgrid, 256, 0, stream>>>(p0, p1, p2, p3, p4, p5, ws, out + 2*NP*32);

  wpf_main<<<NP / PPB, 256, 0, stream>>>(pts, tim, cov6, ws, out);
}